// Round 5
// baseline (239.247 us; speedup 1.0000x reference)
//
#include <hip/hip_runtime.h>
#include <stdint.h>

typedef unsigned short u16;
typedef __attribute__((ext_vector_type(4))) float f32x4;
typedef __attribute__((ext_vector_type(8))) short s16x8;
typedef __attribute__((ext_vector_type(2))) unsigned u32x2;

#define MFMA16(a,b,c) __builtin_amdgcn_mfma_f32_16x16x32_bf16(a,b,c,0,0,0)

__device__ inline u16 f2b(float f){
  unsigned u = __float_as_uint(f);
  unsigned r = u + 0x7fffu + ((u>>16)&1u);
  return (u16)(r>>16);
}
__device__ inline float b2f(u16 b){
  return __uint_as_float(((unsigned)b)<<16);
}
__device__ inline unsigned cvtpk(float lo, float hi){
  unsigned r;
  asm("v_cvt_pk_bf16_f32 %0, %1, %2" : "=v"(r) : "v"(lo), "v"(hi));
  return r;
}
__device__ inline void load_lds16(const void* g, void* l){
  __builtin_amdgcn_global_load_lds((const __attribute__((address_space(1))) void*)g,
                                   (__attribute__((address_space(3))) void*)l, 16, 0, 0);
}

// ---------------------------------------------------------------- input prep (fused)
// blocks [0,8192): x,var_x -> xb bf16, Acat=[var_x|x^2]
// blocks [8192,20480): per z: wmu bf16, Bcat=[w_var+w_mu^2 | w_var]
__global__ void prep_in_kernel(const float* __restrict__ x, const float* __restrict__ vx,
                               const float* __restrict__ w0mu, const float* __restrict__ w0va,
                               const float* __restrict__ w1mu, const float* __restrict__ w1va,
                               const float* __restrict__ w2mu, const float* __restrict__ w2va,
                               u16* __restrict__ xb, u16* __restrict__ acat,
                               u16* __restrict__ wmub, u16* __restrict__ bcat){
  int bid = blockIdx.x;
  if (bid < 8192){
    int i = bid*256 + threadIdx.x;          // 0..2M-1
    int j = i & 1023;
    float xv = x[i];
    xb[i] = f2b(xv);
    size_t ar = (size_t)(i >> 10)*2048;
    acat[ar + j]        = f2b(vx[i]);
    acat[ar + 1024 + j] = f2b(xv*xv);
  } else {
    int t = bid - 8192;
    int z = t >> 12;                        // 0..2
    int i = (t & 4095)*256 + threadIdx.x;   // 0..1M-1
    const float* wmu = z==0?w0mu:(z==1?w1mu:w2mu);
    const float* wva = z==0?w0va:(z==1?w1va:w2va);
    u16* wb = wmub + (size_t)z*1048576;
    u16* bc = bcat + (size_t)z*2097152;
    int j = i & 1023;
    float mu = wmu[i], va = wva[i];
    wb[i] = f2b(mu);
    size_t br = (size_t)(i >> 10)*2048;
    bc[br + j]        = f2b(va + mu*mu);
    bc[br + 1024 + j] = f2b(va);
  }
}

// ---------------------------------------------------------------- NT GEMM bf16
// 6 problems, 1-D grid interleaved (z = bid%6). BK=64, XOR-swizzled LDS chunks
// (pre-swizzled global source, linear global_load_lds dest), operand-swapped
// MFMA so the epilogue packs 4 consecutive N-cols per lane -> 8B stores.
__global__ __launch_bounds__(256) void gemm_nt6_kernel(
    const u16* __restrict__ xb, const u16* __restrict__ acat,
    const u16* __restrict__ wmub, const u16* __restrict__ bcat,
    u16* __restrict__ cbase){
  int bid = blockIdx.x;
  int z = bid % 6;
  int xy = bid / 6;
  int bx = xy & 15, by = xy >> 4;           // 16 M-tiles x 8 N-tiles
  const u16* A = z<3 ? xb : acat;
  int K = z<3 ? 1024 : 2048;
  const u16* B = z<3 ? wmub + (size_t)z*1048576 : bcat + (size_t)(z-3)*2097152;
  u16* C = cbase + (size_t)z*2097152;
  const int N = 1024;
  __shared__ __align__(16) u16 As[128*64];
  __shared__ __align__(16) u16 Bs[128*64];
  int tid = threadIdx.x;
  int wid = tid>>6, lane = tid&63;
  int wr = wid>>1, wc = wid&1;              // wave tile 64x64 in 2x2 grid
  int fr = lane&15, kg = lane>>4;
  int m0 = bx*128, n0 = by*128;
  // staging: 16 chunks of 1KB per tile; chunk c = rows c*8..c*8+7.
  // lane l -> local row l>>3, dest slot l&7; source chunk = (l&7)^(l>>3).
  int srow = lane>>3;
  int sci  = (lane&7) ^ srow;
  f32x4 acc[4][4] = {};
  for (int k0=0; k0<K; k0+=64){
    #pragma unroll
    for (int cc=0; cc<4; cc++){
      int c = wid*4 + cc;
      size_t gra = (size_t)(m0 + c*8 + srow)*K + k0 + sci*8;
      size_t grb = (size_t)(n0 + c*8 + srow)*K + k0 + sci*8;
      load_lds16(A + gra, (char*)As + c*1024);
      load_lds16(B + grb, (char*)Bs + c*1024);
    }
    __syncthreads();
    #pragma unroll
    for (int kf=0;kf<2;kf++){
      s16x8 af[4], bfv[4];
      #pragma unroll
      for (int i=0;i<4;i++){
        int Ra = wr*64 + i*16 + fr;
        int Rb = wc*64 + i*16 + fr;
        af[i]  = *(const s16x8*)(As + Ra*64 + (((kg + kf*4) ^ (Ra&7))<<3));
        bfv[i] = *(const s16x8*)(Bs + Rb*64 + (((kg + kf*4) ^ (Rb&7))<<3));
      }
      #pragma unroll
      for (int i=0;i<4;i++)
        #pragma unroll
        for (int j=0;j<4;j++)
          acc[i][j] = MFMA16(bfv[j], af[i], acc[i][j]);
    }
    __syncthreads();
  }
  // epilogue: lane holds rows m (=fr), 4 consecutive n per (i,j) -> packed 8B
  #pragma unroll
  for (int i=0;i<4;i++){
    int mrow = m0 + wr*64 + i*16 + fr;
    #pragma unroll
    for (int j=0;j<4;j++){
      int ncol = n0 + wc*64 + j*16 + kg*4;
      u32x2 pk = {cvtpk(acc[i][j][0],acc[i][j][1]), cvtpk(acc[i][j][2],acc[i][j][3])};
      *(u32x2*)(C + (size_t)mrow*N + ncol) = pk;
    }
  }
}

// ---------------------------------------------------------------- mid (fused)
// blocks [0,6144): transpose slices z=0: v->vT, z=1: vv+v^2->vw2T, z=2: vv->vvT
// blocks [6144,14336): kw2 = vk + k^2 elementwise
__global__ void mid_kernel(const u16* __restrict__ kb, const u16* __restrict__ vkb,
                           u16* __restrict__ kw2,
                           const u16* __restrict__ vb, const u16* __restrict__ vvb,
                           u16* __restrict__ vT, u16* __restrict__ vw2T,
                           u16* __restrict__ vvT){
  __shared__ u16 t[32][33];
  int bid = blockIdx.x;
  if (bid < 6144){
    int z = bid / 2048, wI = bid % 2048;
    int bx = wI & 31, by = wI >> 5;
    u16* out = z==0?vT:(z==1?vw2T:vvT);
    int tx = threadIdx.x & 31, ty = threadIdx.x >> 5;
    int c0 = bx*32, r0 = by*32;
    #pragma unroll
    for (int rr=0; rr<32; rr+=8){
      size_t idx = (size_t)(r0+ty+rr)*1024 + c0+tx;
      u16 val;
      if (z==0)      val = vb[idx];
      else if (z==2) val = vvb[idx];
      else {
        float v  = b2f(vb[idx]);
        float vv = b2f(vvb[idx]);
        val = f2b(vv + v*v);
      }
      t[ty+rr][tx] = val;
    }
    __syncthreads();
    #pragma unroll
    for (int rr=0; rr<32; rr+=8)
      out[(size_t)(c0+ty+rr)*2048 + r0+tx] = t[tx][ty+rr];
  } else {
    int i = (bid - 6144)*256 + threadIdx.x;  // 0..2M-1
    float kk = b2f(kb[i]);
    float vk = b2f(vkb[i]);
    kw2[i] = f2b(vk + kk*kk);
  }
}

// ---------------------------------------------------------------- fused VDP attention
// grid (16 qblks of 64 rows, 16 heads, 2 batch), 4 waves x 16 q-rows.
// Swapped-operand QK^T (q lane-local), scalar softmax (no max needed),
// cvt_pk packed plds round-trip, LDS-staged double-buffered KV tiles.
// q^2 fragments computed in-register from qa (no qsq tensor).
__global__ __launch_bounds__(256) void attn_vdp_kernel(
  const u16* __restrict__ qb, const u16* __restrict__ vqb,
  const u16* __restrict__ kb, const u16* __restrict__ kw2, const u16* __restrict__ vkb,
  const u16* __restrict__ vT, const u16* __restrict__ vw2T, const u16* __restrict__ vvT,
  const float* __restrict__ x, float* __restrict__ out0, float* __restrict__ out1){
  int qblk = blockIdx.x, h = blockIdx.y, b = blockIdx.z;
  int wid = threadIdx.x>>6, lane = threadIdx.x&63;
  int fr = lane&15, kg = lane>>4;
  int qrow0 = qblk*64 + wid*16;
  size_t mbase = (size_t)b*1024;

  __shared__ __align__(16) u16 bufA[3][4096];        // K-set: kb, kw2, vkb  [64][64]
  __shared__ __align__(16) u16 bufB[3][4096];        // V-set: vT, vw2T, vvT [64][64]
  __shared__ __align__(16) u16 plds[4][3][16][72];   // per-wave P/vP/P^2, row = q

  const int srow = lane>>3;
  const int sci  = (lane&7) ^ srow;
  const int c0   = wid*2;                            // this wave's 2 chunks

  auto stA1 = [&](int jt, u16* dst){                 // K mean only (pass A)
    size_t base = (mbase + (size_t)jt*64)*1024 + h*64;
    #pragma unroll
    for (int c2=0;c2<2;c2++){
      int c = c0+c2;
      size_t go = base + (size_t)(c*8+srow)*1024 + sci*8;
      load_lds16(kb + go, (char*)dst + c*1024);
    }
  };
  auto stK3 = [&](int jt){                           // full K-set -> bufA
    size_t base = (mbase + (size_t)jt*64)*1024 + h*64;
    #pragma unroll
    for (int c2=0;c2<2;c2++){
      int c = c0+c2;
      size_t go = base + (size_t)(c*8+srow)*1024 + sci*8;
      load_lds16(kb  + go, (char*)bufA[0] + c*1024);
      load_lds16(kw2 + go, (char*)bufA[1] + c*1024);
      load_lds16(vkb + go, (char*)bufA[2] + c*1024);
    }
  };
  auto stV3 = [&](int jt){                           // full V-set -> bufB
    size_t base = (size_t)(h*64)*2048 + mbase + (size_t)jt*64;
    #pragma unroll
    for (int c2=0;c2<2;c2++){
      int c = c0+c2;
      size_t go = base + (size_t)(c*8+srow)*2048 + sci*8;
      load_lds16(vT   + go, (char*)bufB[0] + c*1024);
      load_lds16(vw2T + go, (char*)bufB[1] + c*1024);
      load_lds16(vvT  + go, (char*)bufB[2] + c*1024);
    }
  };
  auto frag = [&](const u16* t, int ni, int kf)->s16x8{
    int R = ni*16+fr;
    return *(const s16x8*)(t + R*64 + (((kg + kf*4) ^ (R&7))<<3));
  };

  // Q-side fragments (row = fr, k = kg*8 + kf*32); q^2 computed in-register
  s16x8 qa[2], vqa[2], qsa[2];
  {
    size_t ro = (mbase + qrow0 + fr)*1024 + h*64 + kg*8;
    #pragma unroll
    for (int kf=0;kf<2;kf++){
      qa[kf]  = *(const s16x8*)(qb  + ro + kf*32);
      vqa[kf] = *(const s16x8*)(vqb + ro + kf*32);
      #pragma unroll
      for (int e=0;e<8;e+=2){
        float lo = b2f((u16)qa[kf][e]);
        float hi = b2f((u16)qa[kf][e+1]);
        unsigned pk = cvtpk(lo*lo, hi*hi);
        qsa[kf][e]   = (short)(pk & 0xffffu);
        qsa[kf][e+1] = (short)(pk >> 16);
      }
    }
  }
  const float scale = 0.03125f;         // 1/sqrt(1024)

  // -------- pass A: per-lane sum of exp(score) (no max; |s| <~ 2)
  float lsum = 0.f;
  stA1(0, bufA[0]);
  __syncthreads();
  for (int jt=0;jt<16;jt++){
    const u16* cur = (jt&1) ? bufB[0] : bufA[0];
    if (jt<15) stA1(jt+1, (jt&1) ? bufA[0] : bufB[0]);
    else       stK3(0);                 // pre-stage K-set for pass B
    f32x4 sacc[4] = {};
    #pragma unroll
    for (int ni=0;ni<4;ni++)
      #pragma unroll
      for (int kf=0;kf<2;kf++)
        sacc[ni] = MFMA16(frag(cur,ni,kf), qa[kf], sacc[ni]);
    #pragma unroll
    for (int ni=0;ni<4;ni++)
      #pragma unroll
      for (int r=0;r<4;r++)
        lsum += __expf(sacc[ni][r]*scale);
    __syncthreads();
  }
  lsum += __shfl_xor(lsum, 16);
  lsum += __shfl_xor(lsum, 32);
  const float linv = 1.f/lsum;

  // -------- pass B
  f32x4 omu[4] = {}, ova[4] = {};
  for (int jt=0;jt<16;jt++){
    // ---- phase S
    stV3(jt);
    f32x4 sacc[4] = {}, vacc[4] = {};
    #pragma unroll
    for (int ni=0;ni<4;ni++)
      #pragma unroll
      for (int kf=0;kf<2;kf++){
        sacc[ni] = MFMA16(frag(bufA[0],ni,kf), qa[kf],  sacc[ni]);
        vacc[ni] = MFMA16(frag(bufA[1],ni,kf), vqa[kf], vacc[ni]);
        vacc[ni] = MFMA16(frag(bufA[2],ni,kf), qsa[kf], vacc[ni]);
      }
    #pragma unroll
    for (int ni=0;ni<4;ni++){
      float pv[4], vpv[4], psv[4];
      #pragma unroll
      for (int r=0;r<4;r++){
        float p  = __expf(sacc[ni][r]*scale) * linv;
        float va = vacc[ni][r] * 9.765625e-4f;   // /1024
        float g  = p*(1.f-p);
        pv[r]  = p;
        vpv[r] = g*g*va;
        psv[r] = p*p;
      }
      *(u32x2*)&plds[wid][0][fr][ni*16+kg*4] = (u32x2){cvtpk(pv[0],pv[1]),   cvtpk(pv[2],pv[3])};
      *(u32x2*)&plds[wid][1][fr][ni*16+kg*4] = (u32x2){cvtpk(vpv[0],vpv[1]), cvtpk(vpv[2],vpv[3])};
      *(u32x2*)&plds[wid][2][fr][ni*16+kg*4] = (u32x2){cvtpk(psv[0],psv[1]), cvtpk(psv[2],psv[3])};
    }
    s16x8 pa[2], vpa[2], pqa[2];
    #pragma unroll
    for (int kf=0;kf<2;kf++){
      pa[kf]  = *(const s16x8*)&plds[wid][0][fr][kf*32 + kg*8];
      vpa[kf] = *(const s16x8*)&plds[wid][1][fr][kf*32 + kg*8];
      pqa[kf] = *(const s16x8*)&plds[wid][2][fr][kf*32 + kg*8];
    }
    __syncthreads();                     // V-set staged; all waves done with bufA
    // ---- phase V
    if (jt<15) stK3(jt+1);
    #pragma unroll
    for (int ni=0;ni<4;ni++)
      #pragma unroll
      for (int kf=0;kf<2;kf++){
        omu[ni] = MFMA16(pa[kf],  frag(bufB[0],ni,kf), omu[ni]);
        ova[ni] = MFMA16(vpa[kf], frag(bufB[1],ni,kf), ova[ni]);
        ova[ni] = MFMA16(pqa[kf], frag(bufB[2],ni,kf), ova[ni]);
      }
    __syncthreads();                     // K-set staged; all waves done with bufB
  }

  // -------- epilogue: residual add + f32 stores
  #pragma unroll
  for (int ni=0;ni<4;ni++){
    #pragma unroll
    for (int r=0;r<4;r++){
      size_t idx = (mbase + qrow0 + kg*4 + r)*1024 + h*64 + ni*16 + fr;
      out0[idx] = x[idx] + omu[ni][r];
      out1[idx] = ova[ni][r];
    }
  }
}

// ---------------------------------------------------------------- launcher
extern "C" void kernel_launch(void* const* d_in, const int* in_sizes, int n_in,
                              void* d_out, int out_size, void* d_ws, size_t ws_size,
                              hipStream_t stream){
  const float* x    = (const float*)d_in[0];
  const float* vx   = (const float*)d_in[1];
  const float* wqmu = (const float*)d_in[2];
  const float* wqva = (const float*)d_in[3];
  const float* wkmu = (const float*)d_in[4];
  const float* wkva = (const float*)d_in[5];
  const float* wvmu = (const float*)d_in[6];
  const float* wvva = (const float*)d_in[7];
  float* out0 = (float*)d_out;
  float* out1 = out0 + 2u*1024u*1024u;

  char* w = (char*)d_ws;
  const size_t MB = 1024*1024;
  u16* xb   = (u16*)(w +  0*MB);   // [2048][1024]
  u16* acat = (u16*)(w +  4*MB);   // [2048][2048]
  u16* wmub = (u16*)(w + 12*MB);   // 3 x [1024][1024]
  u16* bcat = (u16*)(w + 18*MB);   // 3 x [1024][2048]
  u16* qb_  = (u16*)(w + 30*MB);   // 6 x 4MB contiguous: q,k,v,vq,vk,vv
  u16* kb_  = (u16*)(w + 34*MB);
  u16* vb_  = (u16*)(w + 38*MB);
  u16* vqb  = (u16*)(w + 42*MB);
  u16* vkb  = (u16*)(w + 46*MB);
  u16* vvb  = (u16*)(w + 50*MB);
  u16* kw2  = (u16*)(w + 54*MB);
  u16* vT   = (u16*)(w + 58*MB);   // [1024][2048]
  u16* vw2T = (u16*)(w + 62*MB);
  u16* vvT  = (u16*)(w + 66*MB);   // end: 70 MB

  prep_in_kernel<<<20480, 256, 0, stream>>>(x, vx, wqmu, wqva, wkmu, wkva, wvmu, wvva,
                                            xb, acat, wmub, bcat);
  gemm_nt6_kernel<<<768, 256, 0, stream>>>(xb, acat, wmub, bcat, qb_);
  mid_kernel<<<14336, 256, 0, stream>>>(kb_, vkb, kw2, vb_, vvb, vT, vw2T, vvT);
  attn_vdp_kernel<<<dim3(16,16,2), 256, 0, stream>>>(qb_, vqb, kb_, kw2, vkb,
                                                     vT, vw2T, vvT, x, out0, out1);
}

// Round 6
// 214.350 us; speedup vs baseline: 1.1161x; 1.1161x over previous
//
#include <hip/hip_runtime.h>
#include <stdint.h>

typedef unsigned short u16;
typedef __attribute__((ext_vector_type(4))) float f32x4;
typedef __attribute__((ext_vector_type(8))) short s16x8;
typedef __attribute__((ext_vector_type(2))) unsigned u32x2;

#define MFMA16(a,b,c) __builtin_amdgcn_mfma_f32_16x16x32_bf16(a,b,c,0,0,0)

__device__ inline u16 f2b(float f){
  unsigned u = __float_as_uint(f);
  unsigned r = u + 0x7fffu + ((u>>16)&1u);
  return (u16)(r>>16);
}
__device__ inline float b2f(u16 b){
  return __uint_as_float(((unsigned)b)<<16);
}
__device__ inline unsigned cvtpk(float lo, float hi){
  unsigned r;
  asm("v_cvt_pk_bf16_f32 %0, %1, %2" : "=v"(r) : "v"(lo), "v"(hi));
  return r;
}
__device__ inline void load_lds16(const void* g, void* l){
  __builtin_amdgcn_global_load_lds((const __attribute__((address_space(1))) void*)g,
                                   (__attribute__((address_space(3))) void*)l, 16, 0, 0);
}

// ---------------------------------------------------------------- input prep (fused)
__global__ void prep_in_kernel(const float* __restrict__ x, const float* __restrict__ vx,
                               const float* __restrict__ w0mu, const float* __restrict__ w0va,
                               const float* __restrict__ w1mu, const float* __restrict__ w1va,
                               const float* __restrict__ w2mu, const float* __restrict__ w2va,
                               u16* __restrict__ xb, u16* __restrict__ acat,
                               u16* __restrict__ wmub, u16* __restrict__ bcat){
  int bid = blockIdx.x;
  if (bid < 8192){
    int i = bid*256 + threadIdx.x;          // 0..2M-1
    int j = i & 1023;
    float xv = x[i];
    xb[i] = f2b(xv);
    size_t ar = (size_t)(i >> 10)*2048;
    acat[ar + j]        = f2b(vx[i]);
    acat[ar + 1024 + j] = f2b(xv*xv);
  } else {
    int t = bid - 8192;
    int z = t >> 12;                        // 0..2
    int i = (t & 4095)*256 + threadIdx.x;   // 0..1M-1
    const float* wmu = z==0?w0mu:(z==1?w1mu:w2mu);
    const float* wva = z==0?w0va:(z==1?w1va:w2va);
    u16* wb = wmub + (size_t)z*1048576;
    u16* bc = bcat + (size_t)z*2097152;
    int j = i & 1023;
    float mu = wmu[i], va = wva[i];
    wb[i] = f2b(mu);
    size_t br = (size_t)(i >> 10)*2048;
    bc[br + j]        = f2b(va + mu*mu);
    bc[br + 1024 + j] = f2b(va);
  }
}

// ---------------------------------------------------------------- NT GEMM bf16
// Round-4 skeleton (BK=32, 3-D grid, linear [row][32] LDS) + LDS double-buffer:
// stage(next) issued BEFORE compute, barrier (implicit vmcnt(0)) AFTER compute,
// so the next tile's global_load_lds fly under the MFMAs. Operand-swapped MFMA
// -> lane holds 4 consecutive N cols -> packed cvt_pk 8B C-stores.
__global__ __launch_bounds__(256) void gemm_nt6_kernel(
    const u16* __restrict__ xb, const u16* __restrict__ acat,
    const u16* __restrict__ wmub, const u16* __restrict__ bcat,
    u16* __restrict__ cbase){
  int z = blockIdx.z;
  const u16* A = z<3 ? xb : acat;
  int K = z<3 ? 1024 : 2048;
  const u16* B = z<3 ? wmub + (size_t)z*1048576 : bcat + (size_t)(z-3)*2097152;
  u16* C = cbase + (size_t)z*2097152;
  const int N = 1024;
  __shared__ __align__(16) u16 As[2][128*32];
  __shared__ __align__(16) u16 Bs[2][128*32];
  int tid = threadIdx.x;
  int wid = tid>>6, lane = tid&63;
  int wr = wid>>1, wc = wid&1;              // wave tile 64x64 in 2x2 grid
  int fr = lane&15, kg = lane>>4;
  int m0 = blockIdx.x*128, n0 = blockIdx.y*128;
  int srow = lane>>2;                       // staging row 0..15
  int scol = (lane&3)*8;                    // ushort offset

  auto stage = [&](int buf, int k0){
    #pragma unroll
    for (int c=0;c<2;c++){
      int r = c*64 + wid*16 + srow;
      load_lds16(A + (size_t)(m0+r)*K + k0 + scol, (char*)As[buf] + (size_t)(c*64+wid*16)*64);
      load_lds16(B + (size_t)(n0+r)*K + k0 + scol, (char*)Bs[buf] + (size_t)(c*64+wid*16)*64);
    }
  };

  f32x4 acc[4][4] = {};
  stage(0, 0);
  __syncthreads();
  int cur = 0;
  for (int k0=0; k0<K; k0+=32){
    if (k0+32<K) stage(cur^1, k0+32);       // next-tile loads fly under compute
    s16x8 af[4], bfv[4];
    #pragma unroll
    for (int i=0;i<4;i++){
      af[i]  = *(const s16x8*)(As[cur] + (wr*64 + i*16 + fr)*32 + kg*8);
      bfv[i] = *(const s16x8*)(Bs[cur] + (wc*64 + i*16 + fr)*32 + kg*8);
    }
    #pragma unroll
    for (int i=0;i<4;i++)
      #pragma unroll
      for (int j=0;j<4;j++)
        acc[i][j] = MFMA16(bfv[j], af[i], acc[i][j]);
    __syncthreads();                        // drains next-tile loads post-compute
    cur ^= 1;
  }
  // epilogue: lane = row m (fr), 4 consecutive n per (i,j) -> packed 8B stores
  #pragma unroll
  for (int i=0;i<4;i++){
    int mrow = m0 + wr*64 + i*16 + fr;
    #pragma unroll
    for (int j=0;j<4;j++){
      int ncol = n0 + wc*64 + j*16 + kg*4;
      u32x2 pk = {cvtpk(acc[i][j][0],acc[i][j][1]), cvtpk(acc[i][j][2],acc[i][j][3])};
      *(u32x2*)(C + (size_t)mrow*N + ncol) = pk;
    }
  }
}

// ---------------------------------------------------------------- mid (fused)
__global__ void mid_kernel(const u16* __restrict__ kb, const u16* __restrict__ vkb,
                           u16* __restrict__ kw2,
                           const u16* __restrict__ vb, const u16* __restrict__ vvb,
                           u16* __restrict__ vT, u16* __restrict__ vw2T,
                           u16* __restrict__ vvT){
  __shared__ u16 t[32][33];
  int bid = blockIdx.x;
  if (bid < 6144){
    int z = bid / 2048, wI = bid % 2048;
    int bx = wI & 31, by = wI >> 5;
    u16* out = z==0?vT:(z==1?vw2T:vvT);
    int tx = threadIdx.x & 31, ty = threadIdx.x >> 5;
    int c0 = bx*32, r0 = by*32;
    #pragma unroll
    for (int rr=0; rr<32; rr+=8){
      size_t idx = (size_t)(r0+ty+rr)*1024 + c0+tx;
      u16 val;
      if (z==0)      val = vb[idx];
      else if (z==2) val = vvb[idx];
      else {
        float v  = b2f(vb[idx]);
        float vv = b2f(vvb[idx]);
        val = f2b(vv + v*v);
      }
      t[ty+rr][tx] = val;
    }
    __syncthreads();
    #pragma unroll
    for (int rr=0; rr<32; rr+=8)
      out[(size_t)(c0+ty+rr)*2048 + r0+tx] = t[tx][ty+rr];
  } else {
    int i = (bid - 6144)*256 + threadIdx.x;  // 0..2M-1
    float kk = b2f(kb[i]);
    float vk = b2f(vkb[i]);
    kw2[i] = f2b(vk + kk*kk);
  }
}

// ---------------------------------------------------------------- fused VDP attention
__global__ __launch_bounds__(256) void attn_vdp_kernel(
  const u16* __restrict__ qb, const u16* __restrict__ vqb,
  const u16* __restrict__ kb, const u16* __restrict__ kw2, const u16* __restrict__ vkb,
  const u16* __restrict__ vT, const u16* __restrict__ vw2T, const u16* __restrict__ vvT,
  const float* __restrict__ x, float* __restrict__ out0, float* __restrict__ out1){
  int qblk = blockIdx.x, h = blockIdx.y, b = blockIdx.z;
  int wid = threadIdx.x>>6, lane = threadIdx.x&63;
  int fr = lane&15, kg = lane>>4;
  int qrow0 = qblk*64 + wid*16;
  size_t mbase = (size_t)b*1024;

  __shared__ __align__(16) u16 bufA[3][4096];        // K-set: kb, kw2, vkb  [64][64]
  __shared__ __align__(16) u16 bufB[3][4096];        // V-set: vT, vw2T, vvT [64][64]
  __shared__ __align__(16) u16 plds[4][3][16][72];   // per-wave P/vP/P^2, row = q

  const int srow = lane>>3;
  const int sci  = (lane&7) ^ srow;
  const int c0   = wid*2;                            // this wave's 2 chunks

  auto stA1 = [&](int jt, u16* dst){                 // K mean only (pass A)
    size_t base = (mbase + (size_t)jt*64)*1024 + h*64;
    #pragma unroll
    for (int c2=0;c2<2;c2++){
      int c = c0+c2;
      size_t go = base + (size_t)(c*8+srow)*1024 + sci*8;
      load_lds16(kb + go, (char*)dst + c*1024);
    }
  };
  auto stK3 = [&](int jt){                           // full K-set -> bufA
    size_t base = (mbase + (size_t)jt*64)*1024 + h*64;
    #pragma unroll
    for (int c2=0;c2<2;c2++){
      int c = c0+c2;
      size_t go = base + (size_t)(c*8+srow)*1024 + sci*8;
      load_lds16(kb  + go, (char*)bufA[0] + c*1024);
      load_lds16(kw2 + go, (char*)bufA[1] + c*1024);
      load_lds16(vkb + go, (char*)bufA[2] + c*1024);
    }
  };
  auto stV3 = [&](int jt){                           // full V-set -> bufB
    size_t base = (size_t)(h*64)*2048 + mbase + (size_t)jt*64;
    #pragma unroll
    for (int c2=0;c2<2;c2++){
      int c = c0+c2;
      size_t go = base + (size_t)(c*8+srow)*2048 + sci*8;
      load_lds16(vT   + go, (char*)bufB[0] + c*1024);
      load_lds16(vw2T + go, (char*)bufB[1] + c*1024);
      load_lds16(vvT  + go, (char*)bufB[2] + c*1024);
    }
  };
  auto frag = [&](const u16* t, int ni, int kf)->s16x8{
    int R = ni*16+fr;
    return *(const s16x8*)(t + R*64 + (((kg + kf*4) ^ (R&7))<<3));
  };

  // Q-side fragments; q^2 computed in-register
  s16x8 qa[2], vqa[2], qsa[2];
  {
    size_t ro = (mbase + qrow0 + fr)*1024 + h*64 + kg*8;
    #pragma unroll
    for (int kf=0;kf<2;kf++){
      qa[kf]  = *(const s16x8*)(qb  + ro + kf*32);
      vqa[kf] = *(const s16x8*)(vqb + ro + kf*32);
      #pragma unroll
      for (int e=0;e<8;e+=2){
        float lo = b2f((u16)qa[kf][e]);
        float hi = b2f((u16)qa[kf][e+1]);
        unsigned pk = cvtpk(lo*lo, hi*hi);
        qsa[kf][e]   = (short)(pk & 0xffffu);
        qsa[kf][e+1] = (short)(pk >> 16);
      }
    }
  }
  const float scale = 0.03125f;         // 1/sqrt(1024)

  // -------- pass A: per-lane sum of exp(score) (no max; |s| <~ 2)
  float lsum = 0.f;
  stA1(0, bufA[0]);
  __syncthreads();
  for (int jt=0;jt<16;jt++){
    const u16* cur = (jt&1) ? bufB[0] : bufA[0];
    if (jt<15) stA1(jt+1, (jt&1) ? bufA[0] : bufB[0]);
    else       stK3(0);                 // pre-stage K-set for pass B
    f32x4 sacc[4] = {};
    __builtin_amdgcn_s_setprio(1);
    #pragma unroll
    for (int ni=0;ni<4;ni++)
      #pragma unroll
      for (int kf=0;kf<2;kf++)
        sacc[ni] = MFMA16(frag(cur,ni,kf), qa[kf], sacc[ni]);
    __builtin_amdgcn_s_setprio(0);
    #pragma unroll
    for (int ni=0;ni<4;ni++)
      #pragma unroll
      for (int r=0;r<4;r++)
        lsum += __expf(sacc[ni][r]*scale);
    __syncthreads();
  }
  lsum += __shfl_xor(lsum, 16);
  lsum += __shfl_xor(lsum, 32);
  const float linv = 1.f/lsum;

  // -------- pass B
  f32x4 omu[4] = {}, ova[4] = {};
  for (int jt=0;jt<16;jt++){
    // ---- phase S
    stV3(jt);
    f32x4 sacc[4] = {}, vacc[4] = {};
    __builtin_amdgcn_s_setprio(1);
    #pragma unroll
    for (int ni=0;ni<4;ni++)
      #pragma unroll
      for (int kf=0;kf<2;kf++){
        sacc[ni] = MFMA16(frag(bufA[0],ni,kf), qa[kf],  sacc[ni]);
        vacc[ni] = MFMA16(frag(bufA[1],ni,kf), vqa[kf], vacc[ni]);
        vacc[ni] = MFMA16(frag(bufA[2],ni,kf), qsa[kf], vacc[ni]);
      }
    __builtin_amdgcn_s_setprio(0);
    #pragma unroll
    for (int ni=0;ni<4;ni++){
      float pv[4], vpv[4], psv[4];
      #pragma unroll
      for (int r=0;r<4;r++){
        float p  = __expf(sacc[ni][r]*scale) * linv;
        float va = vacc[ni][r] * 9.765625e-4f;   // /1024
        float g  = p*(1.f-p);
        pv[r]  = p;
        vpv[r] = g*g*va;
        psv[r] = p*p;
      }
      *(u32x2*)&plds[wid][0][fr][ni*16+kg*4] = (u32x2){cvtpk(pv[0],pv[1]),   cvtpk(pv[2],pv[3])};
      *(u32x2*)&plds[wid][1][fr][ni*16+kg*4] = (u32x2){cvtpk(vpv[0],vpv[1]), cvtpk(vpv[2],vpv[3])};
      *(u32x2*)&plds[wid][2][fr][ni*16+kg*4] = (u32x2){cvtpk(psv[0],psv[1]), cvtpk(psv[2],psv[3])};
    }
    s16x8 pa[2], vpa[2], pqa[2];
    #pragma unroll
    for (int kf=0;kf<2;kf++){
      pa[kf]  = *(const s16x8*)&plds[wid][0][fr][kf*32 + kg*8];
      vpa[kf] = *(const s16x8*)&plds[wid][1][fr][kf*32 + kg*8];
      pqa[kf] = *(const s16x8*)&plds[wid][2][fr][kf*32 + kg*8];
    }
    __syncthreads();                     // V-set staged; all waves done with bufA
    // ---- phase V
    if (jt<15) stK3(jt+1);
    __builtin_amdgcn_s_setprio(1);
    #pragma unroll
    for (int ni=0;ni<4;ni++)
      #pragma unroll
      for (int kf=0;kf<2;kf++){
        omu[ni] = MFMA16(pa[kf],  frag(bufB[0],ni,kf), omu[ni]);
        ova[ni] = MFMA16(vpa[kf], frag(bufB[1],ni,kf), ova[ni]);
        ova[ni] = MFMA16(pqa[kf], frag(bufB[2],ni,kf), ova[ni]);
      }
    __builtin_amdgcn_s_setprio(0);
    __syncthreads();                     // K-set staged; all waves done with bufB
  }

  // -------- epilogue: residual add + f32 stores
  #pragma unroll
  for (int ni=0;ni<4;ni++){
    #pragma unroll
    for (int r=0;r<4;r++){
      size_t idx = (mbase + qrow0 + kg*4 + r)*1024 + h*64 + ni*16 + fr;
      out0[idx] = x[idx] + omu[ni][r];
      out1[idx] = ova[ni][r];
    }
  }
}

// ---------------------------------------------------------------- launcher
extern "C" void kernel_launch(void* const* d_in, const int* in_sizes, int n_in,
                              void* d_out, int out_size, void* d_ws, size_t ws_size,
                              hipStream_t stream){
  const float* x    = (const float*)d_in[0];
  const float* vx   = (const float*)d_in[1];
  const float* wqmu = (const float*)d_in[2];
  const float* wqva = (const float*)d_in[3];
  const float* wkmu = (const float*)d_in[4];
  const float* wkva = (const float*)d_in[5];
  const float* wvmu = (const float*)d_in[6];
  const float* wvva = (const float*)d_in[7];
  float* out0 = (float*)d_out;
  float* out1 = out0 + 2u*1024u*1024u;

  char* w = (char*)d_ws;
  const size_t MB = 1024*1024;
  u16* xb   = (u16*)(w +  0*MB);   // [2048][1024]
  u16* acat = (u16*)(w +  4*MB);   // [2048][2048]
  u16* wmub = (u16*)(w + 12*MB);   // 3 x [1024][1024]
  u16* bcat = (u16*)(w + 18*MB);   // 3 x [1024][2048]
  u16* qb_  = (u16*)(w + 30*MB);   // 6 x 4MB contiguous: q,k,v,vq,vk,vv
  u16* kb_  = (u16*)(w + 34*MB);
  u16* vb_  = (u16*)(w + 38*MB);
  u16* vqb  = (u16*)(w + 42*MB);
  u16* vkb  = (u16*)(w + 46*MB);
  u16* vvb  = (u16*)(w + 50*MB);
  u16* kw2  = (u16*)(w + 54*MB);
  u16* vT   = (u16*)(w + 58*MB);   // [1024][2048]
  u16* vw2T = (u16*)(w + 62*MB);
  u16* vvT  = (u16*)(w + 66*MB);   // end: 70 MB

  prep_in_kernel<<<20480, 256, 0, stream>>>(x, vx, wqmu, wqva, wkmu, wkva, wvmu, wvva,
                                            xb, acat, wmub, bcat);
  gemm_nt6_kernel<<<dim3(16,8,6), 256, 0, stream>>>(xb, acat, wmub, bcat, qb_);
  mid_kernel<<<14336, 256, 0, stream>>>(kb_, vkb, kw2, vb_, vvb, vT, vw2T, vvT);
  attn_vdp_kernel<<<dim3(16,16,2), 256, 0, stream>>>(qb_, vqb, kb_, kw2, vkb,
                                                     vT, vw2T, vvT, x, out0, out1);
}

// Round 7
// 213.780 us; speedup vs baseline: 1.1191x; 1.0027x over previous
//
#include <hip/hip_runtime.h>
#include <stdint.h>

typedef unsigned short u16;
typedef __attribute__((ext_vector_type(4))) float f32x4;
typedef __attribute__((ext_vector_type(8))) short s16x8;
typedef __attribute__((ext_vector_type(2))) unsigned u32x2;

#define MFMA16(a,b,c) __builtin_amdgcn_mfma_f32_16x16x32_bf16(a,b,c,0,0,0)

__device__ inline u16 f2b(float f){
  unsigned u = __float_as_uint(f);
  unsigned r = u + 0x7fffu + ((u>>16)&1u);
  return (u16)(r>>16);
}
__device__ inline float b2f(u16 b){
  return __uint_as_float(((unsigned)b)<<16);
}
__device__ inline unsigned cvtpk(float lo, float hi){
  unsigned r;
  asm("v_cvt_pk_bf16_f32 %0, %1, %2" : "=v"(r) : "v"(lo), "v"(hi));
  return r;
}
__device__ inline void load_lds16(const void* g, void* l){
  __builtin_amdgcn_global_load_lds((const __attribute__((address_space(1))) void*)g,
                                   (__attribute__((address_space(3))) void*)l, 16, 0, 0);
}

// ---------------------------------------------------------------- input prep (fused, float4)
// blocks [0,2048): x,var_x -> xb bf16, Acat=[var_x|x^2]   (4 f32/thread)
// blocks [2048,5120): per z: wmu bf16, Bcat=[w_var+w_mu^2 | w_var]
__global__ void prep_in_kernel(const float* __restrict__ x, const float* __restrict__ vx,
                               const float* __restrict__ w0mu, const float* __restrict__ w0va,
                               const float* __restrict__ w1mu, const float* __restrict__ w1va,
                               const float* __restrict__ w2mu, const float* __restrict__ w2va,
                               u16* __restrict__ xb, u16* __restrict__ acat,
                               u16* __restrict__ wmub, u16* __restrict__ bcat){
  int bid = blockIdx.x;
  if (bid < 2048){
    int i4 = bid*256 + threadIdx.x;         // 0..512K-1
    int base = i4*4;
    int j = base & 1023;
    float4 xv = *(const float4*)(x + base);
    float4 vv = *(const float4*)(vx + base);
    u32x2 xpk = {cvtpk(xv.x,xv.y), cvtpk(xv.z,xv.w)};
    *(u32x2*)(xb + base) = xpk;
    size_t ar = (size_t)(base >> 10)*2048;
    *(u32x2*)(acat + ar + j) = (u32x2){cvtpk(vv.x,vv.y), cvtpk(vv.z,vv.w)};
    *(u32x2*)(acat + ar + 1024 + j) =
        (u32x2){cvtpk(xv.x*xv.x, xv.y*xv.y), cvtpk(xv.z*xv.z, xv.w*xv.w)};
  } else {
    int t = bid - 2048;
    int z = t >> 10;                        // 0..2
    int i4 = (t & 1023)*256 + threadIdx.x;  // 0..256K-1
    int base = i4*4;
    const float* wmu = z==0?w0mu:(z==1?w1mu:w2mu);
    const float* wva = z==0?w0va:(z==1?w1va:w2va);
    u16* wb = wmub + (size_t)z*1048576;
    u16* bc = bcat + (size_t)z*2097152;
    int j = base & 1023;
    float4 mu = *(const float4*)(wmu + base);
    float4 va = *(const float4*)(wva + base);
    *(u32x2*)(wb + base) = (u32x2){cvtpk(mu.x,mu.y), cvtpk(mu.z,mu.w)};
    size_t br = (size_t)(base >> 10)*2048;
    *(u32x2*)(bc + br + j) =
        (u32x2){cvtpk(va.x+mu.x*mu.x, va.y+mu.y*mu.y),
                cvtpk(va.z+mu.z*mu.z, va.w+mu.w*mu.w)};
    *(u32x2*)(bc + br + 1024 + j) = (u32x2){cvtpk(va.x,va.y), cvtpk(va.z,va.w)};
  }
}

// ---------------------------------------------------------------- NT GEMM bf16
// BK=32, triple-buffered LDS, raw s_barrier + counted s_waitcnt vmcnt(4):
// stage(t+2) each iter; loads stay in flight 2 full iterations. z interleaved
// fastest (bid%6) so K=1024/K=2048 blocks mix per scheduling round.
__global__ __launch_bounds__(256) void gemm_nt6_kernel(
    const u16* __restrict__ xb, const u16* __restrict__ acat,
    const u16* __restrict__ wmub, const u16* __restrict__ bcat,
    u16* __restrict__ cbase){
  int bid = blockIdx.x;
  int z = bid % 6;
  int xy = bid / 6;
  int bx = xy & 15, by = xy >> 4;           // 16 M-tiles x 8 N-tiles
  const u16* A = z<3 ? xb : acat;
  int K = z<3 ? 1024 : 2048;
  const u16* B = z<3 ? wmub + (size_t)z*1048576 : bcat + (size_t)(z-3)*2097152;
  u16* C = cbase + (size_t)z*2097152;
  const int N = 1024;
  __shared__ __align__(16) u16 As0[128*32], As1[128*32], As2[128*32];
  __shared__ __align__(16) u16 Bs0[128*32], Bs1[128*32], Bs2[128*32];
  int tid = threadIdx.x;
  int wid = tid>>6, lane = tid&63;
  int wr = wid>>1, wc = wid&1;              // wave tile 64x64 in 2x2 grid
  int fr = lane&15, kg = lane>>4;
  int m0 = bx*128, n0 = by*128;
  int srow = lane>>2;                       // staging row 0..15
  int scol = (lane&3)*8;                    // ushort offset

  auto stage = [&](u16* Ad, u16* Bd, int k0){
    #pragma unroll
    for (int c=0;c<2;c++){
      int r = c*64 + wid*16 + srow;
      load_lds16(A + (size_t)(m0+r)*K + k0 + scol, (char*)Ad + (size_t)(c*64+wid*16)*64);
      load_lds16(B + (size_t)(n0+r)*K + k0 + scol, (char*)Bd + (size_t)(c*64+wid*16)*64);
    }
  };

  int nt = K >> 5;
  // rolling buffer pointers: Ar = read, An = next (in flight), At = stage target
  u16 *Ar=As0, *An=As1, *At=As2, *Br=Bs0, *Bn=Bs1, *Bt=Bs2;
  stage(Ar, Br, 0);
  stage(An, Bn, 32);
  f32x4 acc[4][4] = {};
  for (int t=0; t<nt; t++){
    if (t < nt-1) asm volatile("s_waitcnt vmcnt(4)" ::: "memory");
    else          asm volatile("s_waitcnt vmcnt(0)" ::: "memory");
    __builtin_amdgcn_s_barrier();           // all waves: stage(t) landed, iter t-1 reads done
    if (t+2 < nt) stage(At, Bt, (t+2)*32);  // overwrites the buffer read at t-1
    s16x8 af[4], bfv[4];
    #pragma unroll
    for (int i=0;i<4;i++){
      af[i]  = *(const s16x8*)(Ar + (wr*64 + i*16 + fr)*32 + kg*8);
      bfv[i] = *(const s16x8*)(Br + (wc*64 + i*16 + fr)*32 + kg*8);
    }
    #pragma unroll
    for (int i=0;i<4;i++)
      #pragma unroll
      for (int j=0;j<4;j++)
        acc[i][j] = MFMA16(bfv[j], af[i], acc[i][j]);
    u16* ta = Ar; Ar = An; An = At; At = ta;
    u16* tb = Br; Br = Bn; Bn = Bt; Bt = tb;
  }
  // epilogue: lane = row m (fr), 4 consecutive n per (i,j) -> packed 8B stores
  #pragma unroll
  for (int i=0;i<4;i++){
    int mrow = m0 + wr*64 + i*16 + fr;
    #pragma unroll
    for (int j=0;j<4;j++){
      int ncol = n0 + wc*64 + j*16 + kg*4;
      u32x2 pk = {cvtpk(acc[i][j][0],acc[i][j][1]), cvtpk(acc[i][j][2],acc[i][j][3])};
      *(u32x2*)(C + (size_t)mrow*N + ncol) = pk;
    }
  }
}

// ---------------------------------------------------------------- mid (fused)
__global__ void mid_kernel(const u16* __restrict__ kb, const u16* __restrict__ vkb,
                           u16* __restrict__ kw2,
                           const u16* __restrict__ vb, const u16* __restrict__ vvb,
                           u16* __restrict__ vT, u16* __restrict__ vw2T,
                           u16* __restrict__ vvT){
  __shared__ u16 t[32][33];
  int bid = blockIdx.x;
  if (bid < 6144){
    int z = bid / 2048, wI = bid % 2048;
    int bx = wI & 31, by = wI >> 5;
    u16* out = z==0?vT:(z==1?vw2T:vvT);
    int tx = threadIdx.x & 31, ty = threadIdx.x >> 5;
    int c0 = bx*32, r0 = by*32;
    #pragma unroll
    for (int rr=0; rr<32; rr+=8){
      size_t idx = (size_t)(r0+ty+rr)*1024 + c0+tx;
      u16 val;
      if (z==0)      val = vb[idx];
      else if (z==2) val = vvb[idx];
      else {
        float v  = b2f(vb[idx]);
        float vv = b2f(vvb[idx]);
        val = f2b(vv + v*v);
      }
      t[ty+rr][tx] = val;
    }
    __syncthreads();
    #pragma unroll
    for (int rr=0; rr<32; rr+=8)
      out[(size_t)(c0+ty+rr)*2048 + r0+tx] = t[tx][ty+rr];
  } else {
    int i = (bid - 6144)*256 + threadIdx.x;  // 0..2M-1
    float kk = b2f(kb[i]);
    float vk = b2f(vkb[i]);
    kw2[i] = f2b(vk + kk*kk);
  }
}

// ---------------------------------------------------------------- fused VDP attention
__global__ __launch_bounds__(256) void attn_vdp_kernel(
  const u16* __restrict__ qb, const u16* __restrict__ vqb,
  const u16* __restrict__ kb, const u16* __restrict__ kw2, const u16* __restrict__ vkb,
  const u16* __restrict__ vT, const u16* __restrict__ vw2T, const u16* __restrict__ vvT,
  const float* __restrict__ x, float* __restrict__ out0, float* __restrict__ out1){
  int qblk = blockIdx.x, h = blockIdx.y, b = blockIdx.z;
  int wid = threadIdx.x>>6, lane = threadIdx.x&63;
  int fr = lane&15, kg = lane>>4;
  int qrow0 = qblk*64 + wid*16;
  size_t mbase = (size_t)b*1024;

  __shared__ __align__(16) u16 bufA[3][4096];        // K-set: kb, kw2, vkb  [64][64]
  __shared__ __align__(16) u16 bufB[3][4096];        // V-set: vT, vw2T, vvT [64][64]
  __shared__ __align__(16) u16 plds[4][3][16][72];   // per-wave P/vP/P^2, row = q

  const int srow = lane>>3;
  const int sci  = (lane&7) ^ srow;
  const int c0   = wid*2;                            // this wave's 2 chunks

  auto stA1 = [&](int jt, u16* dst){                 // K mean only (pass A)
    size_t base = (mbase + (size_t)jt*64)*1024 + h*64;
    #pragma unroll
    for (int c2=0;c2<2;c2++){
      int c = c0+c2;
      size_t go = base + (size_t)(c*8+srow)*1024 + sci*8;
      load_lds16(kb + go, (char*)dst + c*1024);
    }
  };
  auto stK3 = [&](int jt){                           // full K-set -> bufA
    size_t base = (mbase + (size_t)jt*64)*1024 + h*64;
    #pragma unroll
    for (int c2=0;c2<2;c2++){
      int c = c0+c2;
      size_t go = base + (size_t)(c*8+srow)*1024 + sci*8;
      load_lds16(kb  + go, (char*)bufA[0] + c*1024);
      load_lds16(kw2 + go, (char*)bufA[1] + c*1024);
      load_lds16(vkb + go, (char*)bufA[2] + c*1024);
    }
  };
  auto stV3 = [&](int jt){                           // full V-set -> bufB
    size_t base = (size_t)(h*64)*2048 + mbase + (size_t)jt*64;
    #pragma unroll
    for (int c2=0;c2<2;c2++){
      int c = c0+c2;
      size_t go = base + (size_t)(c*8+srow)*2048 + sci*8;
      load_lds16(vT   + go, (char*)bufB[0] + c*1024);
      load_lds16(vw2T + go, (char*)bufB[1] + c*1024);
      load_lds16(vvT  + go, (char*)bufB[2] + c*1024);
    }
  };
  auto frag = [&](const u16* t, int ni, int kf)->s16x8{
    int R = ni*16+fr;
    return *(const s16x8*)(t + R*64 + (((kg + kf*4) ^ (R&7))<<3));
  };

  // Q-side fragments; q^2 computed in-register
  s16x8 qa[2], vqa[2], qsa[2];
  {
    size_t ro = (mbase + qrow0 + fr)*1024 + h*64 + kg*8;
    #pragma unroll
    for (int kf=0;kf<2;kf++){
      qa[kf]  = *(const s16x8*)(qb  + ro + kf*32);
      vqa[kf] = *(const s16x8*)(vqb + ro + kf*32);
      #pragma unroll
      for (int e=0;e<8;e+=2){
        float lo = b2f((u16)qa[kf][e]);
        float hi = b2f((u16)qa[kf][e+1]);
        unsigned pk = cvtpk(lo*lo, hi*hi);
        qsa[kf][e]   = (short)(pk & 0xffffu);
        qsa[kf][e+1] = (short)(pk >> 16);
      }
    }
  }
  const float scale = 0.03125f;         // 1/sqrt(1024)

  // -------- pass A: per-lane sum of exp(score) (no max; |s| <~ 2)
  float lsum = 0.f;
  stA1(0, bufA[0]);
  __syncthreads();
  for (int jt=0;jt<16;jt++){
    const u16* cur = (jt&1) ? bufB[0] : bufA[0];
    if (jt<15) stA1(jt+1, (jt&1) ? bufA[0] : bufB[0]);
    else       stK3(0);                 // pre-stage K-set for pass B
    f32x4 sacc[4] = {};
    __builtin_amdgcn_s_setprio(1);
    #pragma unroll
    for (int ni=0;ni<4;ni++)
      #pragma unroll
      for (int kf=0;kf<2;kf++)
        sacc[ni] = MFMA16(frag(cur,ni,kf), qa[kf], sacc[ni]);
    __builtin_amdgcn_s_setprio(0);
    #pragma unroll
    for (int ni=0;ni<4;ni++)
      #pragma unroll
      for (int r=0;r<4;r++)
        lsum += __expf(sacc[ni][r]*scale);
    __syncthreads();
  }
  lsum += __shfl_xor(lsum, 16);
  lsum += __shfl_xor(lsum, 32);
  const float linv = 1.f/lsum;

  // -------- pass B
  f32x4 omu[4] = {}, ova[4] = {};
  for (int jt=0;jt<16;jt++){
    // ---- phase S
    stV3(jt);
    f32x4 sacc[4] = {}, vacc[4] = {};
    __builtin_amdgcn_s_setprio(1);
    #pragma unroll
    for (int ni=0;ni<4;ni++)
      #pragma unroll
      for (int kf=0;kf<2;kf++){
        sacc[ni] = MFMA16(frag(bufA[0],ni,kf), qa[kf],  sacc[ni]);
        vacc[ni] = MFMA16(frag(bufA[1],ni,kf), vqa[kf], vacc[ni]);
        vacc[ni] = MFMA16(frag(bufA[2],ni,kf), qsa[kf], vacc[ni]);
      }
    __builtin_amdgcn_s_setprio(0);
    #pragma unroll
    for (int ni=0;ni<4;ni++){
      float pv[4], vpv[4], psv[4];
      #pragma unroll
      for (int r=0;r<4;r++){
        float p  = __expf(sacc[ni][r]*scale) * linv;
        float va = vacc[ni][r] * 9.765625e-4f;   // /1024
        float g  = p*(1.f-p);
        pv[r]  = p;
        vpv[r] = g*g*va;
        psv[r] = p*p;
      }
      *(u32x2*)&plds[wid][0][fr][ni*16+kg*4] = (u32x2){cvtpk(pv[0],pv[1]),   cvtpk(pv[2],pv[3])};
      *(u32x2*)&plds[wid][1][fr][ni*16+kg*4] = (u32x2){cvtpk(vpv[0],vpv[1]), cvtpk(vpv[2],vpv[3])};
      *(u32x2*)&plds[wid][2][fr][ni*16+kg*4] = (u32x2){cvtpk(psv[0],psv[1]), cvtpk(psv[2],psv[3])};
    }
    s16x8 pa[2], vpa[2], pqa[2];
    #pragma unroll
    for (int kf=0;kf<2;kf++){
      pa[kf]  = *(const s16x8*)&plds[wid][0][fr][kf*32 + kg*8];
      vpa[kf] = *(const s16x8*)&plds[wid][1][fr][kf*32 + kg*8];
      pqa[kf] = *(const s16x8*)&plds[wid][2][fr][kf*32 + kg*8];
    }
    __syncthreads();                     // V-set staged; all waves done with bufA
    // ---- phase V
    if (jt<15) stK3(jt+1);
    __builtin_amdgcn_s_setprio(1);
    #pragma unroll
    for (int ni=0;ni<4;ni++)
      #pragma unroll
      for (int kf=0;kf<2;kf++){
        omu[ni] = MFMA16(pa[kf],  frag(bufB[0],ni,kf), omu[ni]);
        ova[ni] = MFMA16(vpa[kf], frag(bufB[1],ni,kf), ova[ni]);
        ova[ni] = MFMA16(pqa[kf], frag(bufB[2],ni,kf), ova[ni]);
      }
    __builtin_amdgcn_s_setprio(0);
    __syncthreads();                     // K-set staged; all waves done with bufB
  }

  // -------- epilogue: residual add + f32 stores
  #pragma unroll
  for (int ni=0;ni<4;ni++){
    #pragma unroll
    for (int r=0;r<4;r++){
      size_t idx = (mbase + qrow0 + kg*4 + r)*1024 + h*64 + ni*16 + fr;
      out0[idx] = x[idx] + omu[ni][r];
      out1[idx] = ova[ni][r];
    }
  }
}

// ---------------------------------------------------------------- launcher
extern "C" void kernel_launch(void* const* d_in, const int* in_sizes, int n_in,
                              void* d_out, int out_size, void* d_ws, size_t ws_size,
                              hipStream_t stream){
  const float* x    = (const float*)d_in[0];
  const float* vx   = (const float*)d_in[1];
  const float* wqmu = (const float*)d_in[2];
  const float* wqva = (const float*)d_in[3];
  const float* wkmu = (const float*)d_in[4];
  const float* wkva = (const float*)d_in[5];
  const float* wvmu = (const float*)d_in[6];
  const float* wvva = (const float*)d_in[7];
  float* out0 = (float*)d_out;
  float* out1 = out0 + 2u*1024u*1024u;

  char* w = (char*)d_ws;
  const size_t MB = 1024*1024;
  u16* xb   = (u16*)(w +  0*MB);   // [2048][1024]
  u16* acat = (u16*)(w +  4*MB);   // [2048][2048]
  u16* wmub = (u16*)(w + 12*MB);   // 3 x [1024][1024]
  u16* bcat = (u16*)(w + 18*MB);   // 3 x [1024][2048]
  u16* qb_  = (u16*)(w + 30*MB);   // 6 x 4MB contiguous: q,k,v,vq,vk,vv
  u16* kb_  = (u16*)(w + 34*MB);
  u16* vb_  = (u16*)(w + 38*MB);
  u16* vqb  = (u16*)(w + 42*MB);
  u16* vkb  = (u16*)(w + 46*MB);
  u16* vvb  = (u16*)(w + 50*MB);
  u16* kw2  = (u16*)(w + 54*MB);
  u16* vT   = (u16*)(w + 58*MB);   // [1024][2048]
  u16* vw2T = (u16*)(w + 62*MB);
  u16* vvT  = (u16*)(w + 66*MB);   // end: 70 MB

  prep_in_kernel<<<5120, 256, 0, stream>>>(x, vx, wqmu, wqva, wkmu, wkva, wvmu, wvva,
                                           xb, acat, wmub, bcat);
  gemm_nt6_kernel<<<768, 256, 0, stream>>>(xb, acat, wmub, bcat, qb_);
  mid_kernel<<<14336, 256, 0, stream>>>(kb_, vkb, kw2, vb_, vvb, vT, vw2T, vvT);
  attn_vdp_kernel<<<dim3(16,16,2), 256, 0, stream>>>(qb_, vqb, kb_, kw2, vkb,
                                                     vT, vw2T, vvT, x, out0, out1);
}

// Round 8
// 213.035 us; speedup vs baseline: 1.1230x; 1.0035x over previous
//
#include <hip/hip_runtime.h>
#include <stdint.h>

typedef unsigned short u16;
typedef __attribute__((ext_vector_type(4))) float f32x4;
typedef __attribute__((ext_vector_type(8))) short s16x8;
typedef __attribute__((ext_vector_type(2))) unsigned u32x2;

#define MFMA16(a,b,c) __builtin_amdgcn_mfma_f32_16x16x32_bf16(a,b,c,0,0,0)

__device__ inline u16 f2b(float f){
  unsigned u = __float_as_uint(f);
  unsigned r = u + 0x7fffu + ((u>>16)&1u);
  return (u16)(r>>16);
}
__device__ inline float b2f(u16 b){
  return __uint_as_float(((unsigned)b)<<16);
}
__device__ inline unsigned cvtpk(float lo, float hi){
  unsigned r;
  asm("v_cvt_pk_bf16_f32 %0, %1, %2" : "=v"(r) : "v"(lo), "v"(hi));
  return r;
}
__device__ inline void load_lds16(const void* g, void* l){
  __builtin_amdgcn_global_load_lds((const __attribute__((address_space(1))) void*)g,
                                   (__attribute__((address_space(3))) void*)l, 16, 0, 0);
}

// ---------------------------------------------------------------- input prep (fused, float4)
__global__ void prep_in_kernel(const float* __restrict__ x, const float* __restrict__ vx,
                               const float* __restrict__ w0mu, const float* __restrict__ w0va,
                               const float* __restrict__ w1mu, const float* __restrict__ w1va,
                               const float* __restrict__ w2mu, const float* __restrict__ w2va,
                               u16* __restrict__ xb, u16* __restrict__ acat,
                               u16* __restrict__ wmub, u16* __restrict__ bcat){
  int bid = blockIdx.x;
  if (bid < 2048){
    int i4 = bid*256 + threadIdx.x;         // 0..512K-1
    int base = i4*4;
    int j = base & 1023;
    float4 xv = *(const float4*)(x + base);
    float4 vv = *(const float4*)(vx + base);
    u32x2 xpk = {cvtpk(xv.x,xv.y), cvtpk(xv.z,xv.w)};
    *(u32x2*)(xb + base) = xpk;
    size_t ar = (size_t)(base >> 10)*2048;
    *(u32x2*)(acat + ar + j) = (u32x2){cvtpk(vv.x,vv.y), cvtpk(vv.z,vv.w)};
    *(u32x2*)(acat + ar + 1024 + j) =
        (u32x2){cvtpk(xv.x*xv.x, xv.y*xv.y), cvtpk(xv.z*xv.z, xv.w*xv.w)};
  } else {
    int t = bid - 2048;
    int z = t >> 10;                        // 0..2
    int i4 = (t & 1023)*256 + threadIdx.x;  // 0..256K-1
    int base = i4*4;
    const float* wmu = z==0?w0mu:(z==1?w1mu:w2mu);
    const float* wva = z==0?w0va:(z==1?w1va:w2va);
    u16* wb = wmub + (size_t)z*1048576;
    u16* bc = bcat + (size_t)z*2097152;
    int j = base & 1023;
    float4 mu = *(const float4*)(wmu + base);
    float4 va = *(const float4*)(wva + base);
    *(u32x2*)(wb + base) = (u32x2){cvtpk(mu.x,mu.y), cvtpk(mu.z,mu.w)};
    size_t br = (size_t)(base >> 10)*2048;
    *(u32x2*)(bc + br + j) =
        (u32x2){cvtpk(va.x+mu.x*mu.x, va.y+mu.y*mu.y),
                cvtpk(va.z+mu.z*mu.z, va.w+mu.w*mu.w)};
    *(u32x2*)(bc + br + 1024 + j) = (u32x2){cvtpk(va.x,va.y), cvtpk(va.z,va.w)};
  }
}

// ---------------------------------------------------------------- NT GEMM bf16
// r6 schedule (BK=32, dbuf, stage(t+1) before compute(t), barrier drains after)
// + z-interleaved 1-D grid (L2 sharing) + 16B-slot ADD-rotate swizzle:
// stored_slot = (s + ((R>>1)&3))&3 spreads each quarter-wave's ds_read_b128
// across all 8 LDS 16B-positions (was 2 -> 8-way pile-up, 4 extra cyc/read).
__global__ __launch_bounds__(256) void gemm_nt6_kernel(
    const u16* __restrict__ xb, const u16* __restrict__ acat,
    const u16* __restrict__ wmub, const u16* __restrict__ bcat,
    u16* __restrict__ cbase){
  int bid = blockIdx.x;
  int z = bid % 6;
  int xy = bid / 6;
  int bx = xy & 15, by = xy >> 4;           // 16 M-tiles x 8 N-tiles
  const u16* A = z<3 ? xb : acat;
  int K = z<3 ? 1024 : 2048;
  const u16* B = z<3 ? wmub + (size_t)z*1048576 : bcat + (size_t)(z-3)*2097152;
  u16* C = cbase + (size_t)z*2097152;
  const int N = 1024;
  __shared__ __align__(16) u16 As[2][128*32];
  __shared__ __align__(16) u16 Bs[2][128*32];
  int tid = threadIdx.x;
  int wid = tid>>6, lane = tid&63;
  int wr = wid>>1, wc = wid&1;              // wave tile 64x64 in 2x2 grid
  int fr = lane&15, kg = lane>>4;
  int m0 = bx*128, n0 = by*128;
  // staging: lane l -> row (l>>2), LDS slot (l&3); the data that belongs in
  // stored slot t of row R is source slot s = (t - ((R>>1)&3))&3.
  int srow = lane>>2;                       // staging row 0..15
  int scol = (((lane&3) - ((lane>>3)&3)) & 3) * 8;   // pre-swizzled source col
  // frag read: logical k-slot kg of row R lives at stored slot (kg+((R>>1)&3))&3
  int ks  = ((kg + ((fr>>1)&3)) & 3) * 8;

  auto stage = [&](int buf, int k0){
    #pragma unroll
    for (int c=0;c<2;c++){
      int r = c*64 + wid*16 + srow;
      load_lds16(A + (size_t)(m0+r)*K + k0 + scol, (char*)As[buf] + (size_t)(c*64+wid*16)*64);
      load_lds16(B + (size_t)(n0+r)*K + k0 + scol, (char*)Bs[buf] + (size_t)(c*64+wid*16)*64);
    }
  };

  f32x4 acc[4][4] = {};
  stage(0, 0);
  __syncthreads();
  int cur = 0;
  for (int k0=0; k0<K; k0+=32){
    if (k0+32<K) stage(cur^1, k0+32);       // next-tile loads fly under compute
    s16x8 af[4], bfv[4];
    #pragma unroll
    for (int i=0;i<4;i++){
      af[i]  = *(const s16x8*)(As[cur] + (wr*64 + i*16 + fr)*32 + ks);
      bfv[i] = *(const s16x8*)(Bs[cur] + (wc*64 + i*16 + fr)*32 + ks);
    }
    #pragma unroll
    for (int i=0;i<4;i++)
      #pragma unroll
      for (int j=0;j<4;j++)
        acc[i][j] = MFMA16(bfv[j], af[i], acc[i][j]);
    __syncthreads();                        // drains next-tile loads post-compute
    cur ^= 1;
  }
  // epilogue: lane = row m (fr), 4 consecutive n per (i,j) -> packed 8B stores
  #pragma unroll
  for (int i=0;i<4;i++){
    int mrow = m0 + wr*64 + i*16 + fr;
    #pragma unroll
    for (int j=0;j<4;j++){
      int ncol = n0 + wc*64 + j*16 + kg*4;
      u32x2 pk = {cvtpk(acc[i][j][0],acc[i][j][1]), cvtpk(acc[i][j][2],acc[i][j][3])};
      *(u32x2*)(C + (size_t)mrow*N + ncol) = pk;
    }
  }
}

// ---------------------------------------------------------------- mid (fused)
__global__ void mid_kernel(const u16* __restrict__ kb, const u16* __restrict__ vkb,
                           u16* __restrict__ kw2,
                           const u16* __restrict__ vb, const u16* __restrict__ vvb,
                           u16* __restrict__ vT, u16* __restrict__ vw2T,
                           u16* __restrict__ vvT){
  __shared__ u16 t[32][33];
  int bid = blockIdx.x;
  if (bid < 6144){
    int z = bid / 2048, wI = bid % 2048;
    int bx = wI & 31, by = wI >> 5;
    u16* out = z==0?vT:(z==1?vw2T:vvT);
    int tx = threadIdx.x & 31, ty = threadIdx.x >> 5;
    int c0 = bx*32, r0 = by*32;
    #pragma unroll
    for (int rr=0; rr<32; rr+=8){
      size_t idx = (size_t)(r0+ty+rr)*1024 + c0+tx;
      u16 val;
      if (z==0)      val = vb[idx];
      else if (z==2) val = vvb[idx];
      else {
        float v  = b2f(vb[idx]);
        float vv = b2f(vvb[idx]);
        val = f2b(vv + v*v);
      }
      t[ty+rr][tx] = val;
    }
    __syncthreads();
    #pragma unroll
    for (int rr=0; rr<32; rr+=8)
      out[(size_t)(c0+ty+rr)*2048 + r0+tx] = t[tx][ty+rr];
  } else {
    int i = (bid - 6144)*256 + threadIdx.x;  // 0..2M-1
    float kk = b2f(kb[i]);
    float vk = b2f(vkb[i]);
    kw2[i] = f2b(vk + kk*kk);
  }
}

// ---------------------------------------------------------------- fused VDP attention
__global__ __launch_bounds__(256) void attn_vdp_kernel(
  const u16* __restrict__ qb, const u16* __restrict__ vqb,
  const u16* __restrict__ kb, const u16* __restrict__ kw2, const u16* __restrict__ vkb,
  const u16* __restrict__ vT, const u16* __restrict__ vw2T, const u16* __restrict__ vvT,
  const float* __restrict__ x, float* __restrict__ out0, float* __restrict__ out1){
  int qblk = blockIdx.x, h = blockIdx.y, b = blockIdx.z;
  int wid = threadIdx.x>>6, lane = threadIdx.x&63;
  int fr = lane&15, kg = lane>>4;
  int qrow0 = qblk*64 + wid*16;
  size_t mbase = (size_t)b*1024;

  __shared__ __align__(16) u16 bufA[3][4096];        // K-set: kb, kw2, vkb  [64][64]
  __shared__ __align__(16) u16 bufB[3][4096];        // V-set: vT, vw2T, vvT [64][64]
  __shared__ __align__(16) u16 plds[4][3][16][72];   // per-wave P/vP/P^2, row = q

  const int srow = lane>>3;
  const int sci  = (lane&7) ^ srow;
  const int c0   = wid*2;                            // this wave's 2 chunks

  auto stA1 = [&](int jt, u16* dst){                 // K mean only (pass A)
    size_t base = (mbase + (size_t)jt*64)*1024 + h*64;
    #pragma unroll
    for (int c2=0;c2<2;c2++){
      int c = c0+c2;
      size_t go = base + (size_t)(c*8+srow)*1024 + sci*8;
      load_lds16(kb + go, (char*)dst + c*1024);
    }
  };
  auto stK3 = [&](int jt){                           // full K-set -> bufA
    size_t base = (mbase + (size_t)jt*64)*1024 + h*64;
    #pragma unroll
    for (int c2=0;c2<2;c2++){
      int c = c0+c2;
      size_t go = base + (size_t)(c*8+srow)*1024 + sci*8;
      load_lds16(kb  + go, (char*)bufA[0] + c*1024);
      load_lds16(kw2 + go, (char*)bufA[1] + c*1024);
      load_lds16(vkb + go, (char*)bufA[2] + c*1024);
    }
  };
  auto stV3 = [&](int jt){                           // full V-set -> bufB
    size_t base = (size_t)(h*64)*2048 + mbase + (size_t)jt*64;
    #pragma unroll
    for (int c2=0;c2<2;c2++){
      int c = c0+c2;
      size_t go = base + (size_t)(c*8+srow)*2048 + sci*8;
      load_lds16(vT   + go, (char*)bufB[0] + c*1024);
      load_lds16(vw2T + go, (char*)bufB[1] + c*1024);
      load_lds16(vvT  + go, (char*)bufB[2] + c*1024);
    }
  };
  auto frag = [&](const u16* t, int ni, int kf)->s16x8{
    int R = ni*16+fr;
    return *(const s16x8*)(t + R*64 + (((kg + kf*4) ^ (R&7))<<3));
  };

  // Q-side fragments; q^2 computed in-register
  s16x8 qa[2], vqa[2], qsa[2];
  {
    size_t ro = (mbase + qrow0 + fr)*1024 + h*64 + kg*8;
    #pragma unroll
    for (int kf=0;kf<2;kf++){
      qa[kf]  = *(const s16x8*)(qb  + ro + kf*32);
      vqa[kf] = *(const s16x8*)(vqb + ro + kf*32);
      #pragma unroll
      for (int e=0;e<8;e+=2){
        float lo = b2f((u16)qa[kf][e]);
        float hi = b2f((u16)qa[kf][e+1]);
        unsigned pk = cvtpk(lo*lo, hi*hi);
        qsa[kf][e]   = (short)(pk & 0xffffu);
        qsa[kf][e+1] = (short)(pk >> 16);
      }
    }
  }
  const float scale = 0.03125f;         // 1/sqrt(1024)

  // -------- pass A: per-lane sum of exp(score) (no max; |s| <~ 2)
  float lsum = 0.f;
  stA1(0, bufA[0]);
  __syncthreads();
  for (int jt=0;jt<16;jt++){
    const u16* cur = (jt&1) ? bufB[0] : bufA[0];
    if (jt<15) stA1(jt+1, (jt&1) ? bufA[0] : bufB[0]);
    else       stK3(0);                 // pre-stage K-set for pass B
    f32x4 sacc[4] = {};
    __builtin_amdgcn_s_setprio(1);
    #pragma unroll
    for (int ni=0;ni<4;ni++)
      #pragma unroll
      for (int kf=0;kf<2;kf++)
        sacc[ni] = MFMA16(frag(cur,ni,kf), qa[kf], sacc[ni]);
    __builtin_amdgcn_s_setprio(0);
    #pragma unroll
    for (int ni=0;ni<4;ni++)
      #pragma unroll
      for (int r=0;r<4;r++)
        lsum += __expf(sacc[ni][r]*scale);
    __syncthreads();
  }
  lsum += __shfl_xor(lsum, 16);
  lsum += __shfl_xor(lsum, 32);
  const float linv = 1.f/lsum;

  // -------- pass B
  f32x4 omu[4] = {}, ova[4] = {};
  for (int jt=0;jt<16;jt++){
    // ---- phase S
    stV3(jt);
    f32x4 sacc[4] = {}, vacc[4] = {};
    __builtin_amdgcn_s_setprio(1);
    #pragma unroll
    for (int ni=0;ni<4;ni++)
      #pragma unroll
      for (int kf=0;kf<2;kf++){
        sacc[ni] = MFMA16(frag(bufA[0],ni,kf), qa[kf],  sacc[ni]);
        vacc[ni] = MFMA16(frag(bufA[1],ni,kf), vqa[kf], vacc[ni]);
        vacc[ni] = MFMA16(frag(bufA[2],ni,kf), qsa[kf], vacc[ni]);
      }
    __builtin_amdgcn_s_setprio(0);
    #pragma unroll
    for (int ni=0;ni<4;ni++){
      float pv[4], vpv[4], psv[4];
      #pragma unroll
      for (int r=0;r<4;r++){
        float p  = __expf(sacc[ni][r]*scale) * linv;
        float va = vacc[ni][r] * 9.765625e-4f;   // /1024
        float g  = p*(1.f-p);
        pv[r]  = p;
        vpv[r] = g*g*va;
        psv[r] = p*p;
      }
      *(u32x2*)&plds[wid][0][fr][ni*16+kg*4] = (u32x2){cvtpk(pv[0],pv[1]),   cvtpk(pv[2],pv[3])};
      *(u32x2*)&plds[wid][1][fr][ni*16+kg*4] = (u32x2){cvtpk(vpv[0],vpv[1]), cvtpk(vpv[2],vpv[3])};
      *(u32x2*)&plds[wid][2][fr][ni*16+kg*4] = (u32x2){cvtpk(psv[0],psv[1]), cvtpk(psv[2],psv[3])};
    }
    s16x8 pa[2], vpa[2], pqa[2];
    #pragma unroll
    for (int kf=0;kf<2;kf++){
      pa[kf]  = *(const s16x8*)&plds[wid][0][fr][kf*32 + kg*8];
      vpa[kf] = *(const s16x8*)&plds[wid][1][fr][kf*32 + kg*8];
      pqa[kf] = *(const s16x8*)&plds[wid][2][fr][kf*32 + kg*8];
    }
    __syncthreads();                     // V-set staged; all waves done with bufA
    // ---- phase V
    if (jt<15) stK3(jt+1);
    __builtin_amdgcn_s_setprio(1);
    #pragma unroll
    for (int ni=0;ni<4;ni++)
      #pragma unroll
      for (int kf=0;kf<2;kf++){
        omu[ni] = MFMA16(pa[kf],  frag(bufB[0],ni,kf), omu[ni]);
        ova[ni] = MFMA16(vpa[kf], frag(bufB[1],ni,kf), ova[ni]);
        ova[ni] = MFMA16(pqa[kf], frag(bufB[2],ni,kf), ova[ni]);
      }
    __builtin_amdgcn_s_setprio(0);
    __syncthreads();                     // K-set staged; all waves done with bufB
  }

  // -------- epilogue: residual add + f32 stores
  #pragma unroll
  for (int ni=0;ni<4;ni++){
    #pragma unroll
    for (int r=0;r<4;r++){
      size_t idx = (mbase + qrow0 + kg*4 + r)*1024 + h*64 + ni*16 + fr;
      out0[idx] = x[idx] + omu[ni][r];
      out1[idx] = ova[ni][r];
    }
  }
}

// ---------------------------------------------------------------- launcher
extern "C" void kernel_launch(void* const* d_in, const int* in_sizes, int n_in,
                              void* d_out, int out_size, void* d_ws, size_t ws_size,
                              hipStream_t stream){
  const float* x    = (const float*)d_in[0];
  const float* vx   = (const float*)d_in[1];
  const float* wqmu = (const float*)d_in[2];
  const float* wqva = (const float*)d_in[3];
  const float* wkmu = (const float*)d_in[4];
  const float* wkva = (const float*)d_in[5];
  const float* wvmu = (const float*)d_in[6];
  const float* wvva = (const float*)d_in[7];
  float* out0 = (float*)d_out;
  float* out1 = out0 + 2u*1024u*1024u;

  char* w = (char*)d_ws;
  const size_t MB = 1024*1024;
  u16* xb   = (u16*)(w +  0*MB);   // [2048][1024]
  u16* acat = (u16*)(w +  4*MB);   // [2048][2048]
  u16* wmub = (u16*)(w + 12*MB);   // 3 x [1024][1024]
  u16* bcat = (u16*)(w + 18*MB);   // 3 x [1024][2048]
  u16* qb_  = (u16*)(w + 30*MB);   // 6 x 4MB contiguous: q,k,v,vq,vk,vv
  u16* kb_  = (u16*)(w + 34*MB);
  u16* vb_  = (u16*)(w + 38*MB);
  u16* vqb  = (u16*)(w + 42*MB);
  u16* vkb  = (u16*)(w + 46*MB);
  u16* vvb  = (u16*)(w + 50*MB);
  u16* kw2  = (u16*)(w + 54*MB);
  u16* vT   = (u16*)(w + 58*MB);   // [1024][2048]
  u16* vw2T = (u16*)(w + 62*MB);
  u16* vvT  = (u16*)(w + 66*MB);   // end: 70 MB

  prep_in_kernel<<<5120, 256, 0, stream>>>(x, vx, wqmu, wqva, wkmu, wkva, wvmu, wvva,
                                           xb, acat, wmub, bcat);
  gemm_nt6_kernel<<<768, 256, 0, stream>>>(xb, acat, wmub, bcat, qb_);
  mid_kernel<<<14336, 256, 0, stream>>>(kb_, vkb, kw2, vb_, vvb, vT, vw2T, vvT);
  attn_vdp_kernel<<<dim3(16,16,2), 256, 0, stream>>>(qb_, vqb, kb_, kw2, vkb,
                                                     vT, vw2T, vvT, x, out0, out1);
}